// Round 1
// baseline (303.826 us; speedup 1.0000x reference)
//
#include <hip/hip_runtime.h>

// MultiHeadAttention fused pipeline for MI355X (gfx950)
// B=2, L=2048, D=1024, H=16, Dh=64.  fp32 in/out, bf16 MFMA compute.

typedef short v8s __attribute__((ext_vector_type(8)));
typedef __bf16 v8bf __attribute__((ext_vector_type(8)));
typedef float v4f __attribute__((ext_vector_type(4)));

#define DEV static __device__ __forceinline__

DEV short f2bf(float f) {  // RNE float->bf16 (no NaN inputs here)
  unsigned u = __builtin_bit_cast(unsigned, f);
  u += 0x7FFFu + ((u >> 16) & 1u);
  return (short)(u >> 16);
}

DEV v4f mfma16(v8s a, v8s b, v4f c) {
  return __builtin_amdgcn_mfma_f32_16x16x32_bf16(
      __builtin_bit_cast(v8bf, a), __builtin_bit_cast(v8bf, b), c, 0, 0, 0);
}

#define GLDS16(g, l)                                                         \
  __builtin_amdgcn_global_load_lds(                                          \
      (__attribute__((address_space(1))) void*)(g),                          \
      (__attribute__((address_space(3))) void*)(l), 16, 0, 0)

// ---------------- x -> bf16 ----------------
__global__ __launch_bounds__(256) void k_cvt(const float* __restrict__ x,
                                             short* __restrict__ xb) {
  int i = blockIdx.x * 256 + threadIdx.x;
  float4 v = reinterpret_cast<const float4*>(x)[i];
  short4 o;
  o.x = f2bf(v.x); o.y = f2bf(v.y); o.z = f2bf(v.z); o.w = f2bf(v.w);
  reinterpret_cast<short4*>(xb)[i] = o;
}

// ------------- weight transpose fp32 -> bf16 : dst[n][k] = src[k][n] -------------
__global__ __launch_bounds__(256) void k_tw(const float* __restrict__ wq,
                                            const float* __restrict__ wk,
                                            const float* __restrict__ wv,
                                            const float* __restrict__ wo,
                                            short* __restrict__ wqkvT,
                                            short* __restrict__ woT) {
  __shared__ float t[32][33];
  int wi = blockIdx.z;
  const float* src = (wi == 0) ? wq : (wi == 1) ? wk : (wi == 2) ? wv : wo;
  short* dst = (wi < 3) ? (wqkvT + wi * 1024 * 1024) : woT;
  int n0 = blockIdx.x * 32, k0 = blockIdx.y * 32;
  int tx = threadIdx.x, ty = threadIdx.y;
#pragma unroll
  for (int i = 0; i < 4; i++)
    t[ty + i * 8][tx] = src[(k0 + ty + i * 8) * 1024 + n0 + tx];
  __syncthreads();
#pragma unroll
  for (int i = 0; i < 4; i++)
    dst[(n0 + ty + i * 8) * 1024 + k0 + tx] = f2bf(t[tx][ty + i * 8]);
}

// ------------- GEMM: C[M,N] = A[M,K] * BT[N,K]^T (+bias)  -------------
// MODE 0: A=x_bf16 [4096,1024], BT=wqkvT [3072,1024]; scatter Q/K (B,H,L,64) and VT (B,H,64,L)
// MODE 1: A=ctx [4096,1024],    BT=woT [1024,1024];   out fp32 [4096,1024] + bo
template <int MODE>
__global__ __launch_bounds__(256) void k_gemm(
    const short* __restrict__ A, const short* __restrict__ BT,
    const float* __restrict__ b0, const float* __restrict__ b1,
    const float* __restrict__ b2, short* __restrict__ Qo,
    short* __restrict__ Ko, short* __restrict__ VTo,
    float* __restrict__ outF) {
  constexpr int K = 1024;
  __shared__ short As[128 * 64], Bs[128 * 64];
  const int tid = threadIdx.x;
  const int w = tid >> 6, lane = tid & 63;
  const int wr = w >> 1, wc = w & 1;
  const int bm = blockIdx.y, bn = blockIdx.x;
  const int lr = lane & 15, lg = lane >> 4;

  // staging: thread t covers LDS linear bytes i*4096 + t*16 (row = i*32 + t/8)
  // source column pre-swizzled so swizzled ds_reads see logical data
  const int rA = tid >> 3;                              // 0..31
  const int cbs = ((tid & 7) * 16) ^ ((rA & 7) << 4);   // swizzled byte col
  const short* pA[4];
  const short* pB[4];
#pragma unroll
  for (int i = 0; i < 4; i++) {
    pA[i] = A + (size_t)(bm * 128 + rA + i * 32) * K + (cbs >> 1);
    pB[i] = BT + (size_t)(bn * 128 + rA + i * 32) * K + (cbs >> 1);
  }

  v4f acc[4][4] = {};
  for (int kt = 0; kt < K / 64; ++kt) {
#pragma unroll
    for (int i = 0; i < 4; i++) {
      GLDS16(pA[i] + kt * 64, As + i * 2048 + w * 512);
      GLDS16(pB[i] + kt * 64, Bs + i * 2048 + w * 512);
    }
    __syncthreads();
#pragma unroll
    for (int ks = 0; ks < 2; ++ks) {
      v8s af[4], bf[4];
#pragma unroll
      for (int mf = 0; mf < 4; mf++) {
        int R = wr * 64 + mf * 16 + lr;
        int byo = (R * 128 + ks * 64 + lg * 16) ^ ((R & 7) << 4);
        af[mf] = *reinterpret_cast<const v8s*>(
            reinterpret_cast<const char*>(As) + byo);
      }
#pragma unroll
      for (int nf = 0; nf < 4; nf++) {
        int R = wc * 64 + nf * 16 + lr;
        int byo = (R * 128 + ks * 64 + lg * 16) ^ ((R & 7) << 4);
        bf[nf] = *reinterpret_cast<const v8s*>(
            reinterpret_cast<const char*>(Bs) + byo);
      }
#pragma unroll
      for (int mf = 0; mf < 4; mf++)
#pragma unroll
        for (int nf = 0; nf < 4; nf++)
          acc[mf][nf] = mfma16(af[mf], bf[nf], acc[mf][nf]);
    }
    __syncthreads();
  }

#pragma unroll
  for (int mf = 0; mf < 4; mf++) {
#pragma unroll
    for (int nf = 0; nf < 4; nf++) {
#pragma unroll
      for (int r = 0; r < 4; r++) {
        int mrow = bm * 128 + wr * 64 + mf * 16 + lg * 4 + r;
        int ncol = bn * 128 + wc * 64 + nf * 16 + lr;
        float v = acc[mf][nf][r];
        if constexpr (MODE == 0) {
          int which = ncol >> 10, d = ncol & 1023;
          float bias = (which == 0) ? b0[d] : (which == 1) ? b1[d] : b2[d];
          v += bias;
          int h = d >> 6, dh = d & 63;
          int bb = mrow >> 11, lp = mrow & 2047;
          if (which == 0)
            Qo[((size_t)(bb * 16 + h) * 2048 + lp) * 64 + dh] =
                f2bf(v * 0.125f);  // fold 1/sqrt(Dh) into Q
          else if (which == 1)
            Ko[((size_t)(bb * 16 + h) * 2048 + lp) * 64 + dh] = f2bf(v);
          else
            VTo[((size_t)(bb * 16 + h) * 64 + dh) * 2048 + lp] = f2bf(v);
        } else {
          outF[(size_t)mrow * 1024 + ncol] = v + b0[ncol];
        }
      }
    }
  }
}

// ------------- causal flash attention -------------
// grid (32 qtiles reversed, 32 b*h); 4 waves x 16 q-rows, KV tiles of 64
__global__ __launch_bounds__(256) void k_flash(const short* __restrict__ Qg,
                                               const short* __restrict__ Kg,
                                               const short* __restrict__ VTg,
                                               short* __restrict__ ctx) {
  __shared__ short Kl[64 * 72], Vl[64 * 72], Pl[4][16 * 72];
  const int tid = threadIdx.x, w = tid >> 6, lane = tid & 63;
  const int lr = lane & 15, lg = lane >> 4;
  const int qt = (int)gridDim.x - 1 - (int)blockIdx.x;  // long blocks first
  const int bh = blockIdx.y;

  const size_t qrow0 = (size_t)bh * 2048 + qt * 64 + w * 16 + lr;
  v8s q0 = *reinterpret_cast<const v8s*>(Qg + qrow0 * 64 + lg * 8);
  v8s q1 = *reinterpret_cast<const v8s*>(Qg + qrow0 * 64 + lg * 8 + 32);

  float m_r[4], l_r[4];
  v4f o_[4] = {};
#pragma unroll
  for (int r = 0; r < 4; r++) { m_r[r] = -1e30f; l_r[r] = 0.f; }

  const int sr = tid >> 3, sc = (tid & 7) * 8;
  const short* kbase = Kg + (size_t)bh * 2048 * 64;
  const short* vbase = VTg + (size_t)bh * 64 * 2048;

  for (int kt = 0; kt <= qt; ++kt) {
#pragma unroll
    for (int i = 0; i < 2; i++) {
      int r = sr + i * 32;
      *reinterpret_cast<v8s*>(Kl + r * 72 + sc) =
          *reinterpret_cast<const v8s*>(kbase + (size_t)(kt * 64 + r) * 64 + sc);
      *reinterpret_cast<v8s*>(Vl + r * 72 + sc) =
          *reinterpret_cast<const v8s*>(vbase + (size_t)r * 2048 + kt * 64 + sc);
    }
    __syncthreads();

    v4f s[4] = {};
#pragma unroll
    for (int nf = 0; nf < 4; nf++) {
      v8s k0 = *reinterpret_cast<const v8s*>(Kl + (nf * 16 + lr) * 72 + lg * 8);
      v8s k1 =
          *reinterpret_cast<const v8s*>(Kl + (nf * 16 + lr) * 72 + 32 + lg * 8);
      s[nf] = mfma16(q0, k0, s[nf]);
      s[nf] = mfma16(q1, k1, s[nf]);
    }

    if (kt == qt) {
#pragma unroll
      for (int nf = 0; nf < 4; nf++)
#pragma unroll
        for (int r = 0; r < 4; r++) {
          int key = nf * 16 + lr, qr = w * 16 + lg * 4 + r;
          if (key > qr) s[nf][r] = -1e30f;
        }
    }

    float pm[4], alpha[4], rs[4];
#pragma unroll
    for (int r = 0; r < 4; r++)
      pm[r] = fmaxf(fmaxf(s[0][r], s[1][r]), fmaxf(s[2][r], s[3][r]));
#pragma unroll
    for (int off = 1; off < 16; off <<= 1)
#pragma unroll
      for (int r = 0; r < 4; r++)
        pm[r] = fmaxf(pm[r], __shfl_xor(pm[r], off, 64));

    float p[4][4];
#pragma unroll
    for (int r = 0; r < 4; r++) {
      float mn = fmaxf(m_r[r], pm[r]);
      alpha[r] = __expf(m_r[r] - mn);
      m_r[r] = mn;
      rs[r] = 0.f;
    }
#pragma unroll
    for (int nf = 0; nf < 4; nf++)
#pragma unroll
      for (int r = 0; r < 4; r++) {
        p[nf][r] = __expf(s[nf][r] - m_r[r]);
        rs[r] += p[nf][r];
      }
#pragma unroll
    for (int off = 1; off < 16; off <<= 1)
#pragma unroll
      for (int r = 0; r < 4; r++) rs[r] += __shfl_xor(rs[r], off, 64);
#pragma unroll
    for (int r = 0; r < 4; r++) l_r[r] = l_r[r] * alpha[r] + rs[r];
#pragma unroll
    for (int nf = 0; nf < 4; nf++)
#pragma unroll
      for (int r = 0; r < 4; r++) o_[nf][r] *= alpha[r];

    // P -> per-wave LDS, re-fragment as MFMA A operand
#pragma unroll
    for (int nf = 0; nf < 4; nf++)
#pragma unroll
      for (int r = 0; r < 4; r++)
        Pl[w][(lg * 4 + r) * 72 + nf * 16 + lr] = f2bf(p[nf][r]);

#pragma unroll
    for (int ks = 0; ks < 2; ks++) {
      v8s af =
          *reinterpret_cast<const v8s*>(&Pl[w][lr * 72 + ks * 32 + lg * 8]);
#pragma unroll
      for (int nf = 0; nf < 4; nf++) {
        v8s bv = *reinterpret_cast<const v8s*>(Vl + (nf * 16 + lr) * 72 +
                                               ks * 32 + lg * 8);
        o_[nf] = mfma16(af, bv, o_[nf]);
      }
    }
    __syncthreads();
  }

  const int h = bh & 15, bb = bh >> 4;
#pragma unroll
  for (int r = 0; r < 4; r++) {
    float inv = 1.0f / l_r[r];
    int qr = qt * 64 + w * 16 + lg * 4 + r;
#pragma unroll
    for (int nf = 0; nf < 4; nf++)
      ctx[((size_t)(bb * 2048 + qr)) * 1024 + h * 64 + nf * 16 + lr] =
          f2bf(o_[nf][r] * inv);
  }
}

extern "C" void kernel_launch(void* const* d_in, const int* in_sizes, int n_in,
                              void* d_out, int out_size, void* d_ws,
                              size_t ws_size, hipStream_t stream) {
  (void)in_sizes; (void)n_in; (void)out_size; (void)ws_size;
  const float* x = (const float*)d_in[0];
  // d_in[1] = causal_mask (implemented analytically)
  const float* wq = (const float*)d_in[2];
  const float* bq = (const float*)d_in[3];
  const float* wk = (const float*)d_in[4];
  const float* bk = (const float*)d_in[5];
  const float* wv = (const float*)d_in[6];
  const float* bv = (const float*)d_in[7];
  const float* wo = (const float*)d_in[8];
  const float* bo = (const float*)d_in[9];

  char* ws = (char*)d_ws;
  short* xb = (short*)(ws);                      // 8 MB (reused as ctx later)
  short* wqkvT = (short*)(ws + (8u << 20));      // 6 MB
  short* woT = (short*)(ws + (14u << 20));       // 2 MB
  short* Qb = (short*)(ws + (16u << 20));        // 8 MB
  short* Kb = (short*)(ws + (24u << 20));        // 8 MB
  short* VTb = (short*)(ws + (32u << 20));       // 8 MB
  short* ctx = xb;                               // alias: xb dead after QKV GEMM
  float* out = (float*)d_out;

  k_cvt<<<4096, 256, 0, stream>>>(x, xb);
  k_tw<<<dim3(32, 32, 4), dim3(32, 8), 0, stream>>>(wq, wk, wv, wo, wqkvT, woT);
  k_gemm<0><<<dim3(24, 32), 256, 0, stream>>>(xb, wqkvT, bq, bk, bv, Qb, Kb,
                                              VTb, nullptr);
  k_flash<<<dim3(32, 32), 256, 0, stream>>>(Qb, Kb, VTb, ctx);
  k_gemm<1><<<dim3(8, 32), 256, 0, stream>>>(ctx, woT, bo, nullptr, nullptr,
                                             nullptr, nullptr, nullptr, out);
}

// Round 2
// 275.111 us; speedup vs baseline: 1.1044x; 1.1044x over previous
//
#include <hip/hip_runtime.h>

// MultiHeadAttention fused pipeline for MI355X (gfx950)
// B=2, L=2048, D=1024, H=16, Dh=64.  fp32 in/out, bf16 MFMA compute.

typedef short v8s __attribute__((ext_vector_type(8)));
typedef __bf16 v8bf __attribute__((ext_vector_type(8)));
typedef float v4f __attribute__((ext_vector_type(4)));

#define DEV static __device__ __forceinline__

DEV short f2bf(float f) {  // RNE float->bf16 (no NaN inputs here)
  unsigned u = __builtin_bit_cast(unsigned, f);
  u += 0x7FFFu + ((u >> 16) & 1u);
  return (short)(u >> 16);
}

DEV v4f mfma16(v8s a, v8s b, v4f c) {
  return __builtin_amdgcn_mfma_f32_16x16x32_bf16(
      __builtin_bit_cast(v8bf, a), __builtin_bit_cast(v8bf, b), c, 0, 0, 0);
}

#define GLDS16(g, l)                                                         \
  __builtin_amdgcn_global_load_lds(                                          \
      (__attribute__((address_space(1))) void*)(g),                          \
      (__attribute__((address_space(3))) void*)(l), 16, 0, 0)

// ---------------- x -> bf16 ----------------
__global__ __launch_bounds__(256) void k_cvt(const float* __restrict__ x,
                                             short* __restrict__ xb) {
  int i = blockIdx.x * 256 + threadIdx.x;
  float4 v = reinterpret_cast<const float4*>(x)[i];
  short4 o;
  o.x = f2bf(v.x); o.y = f2bf(v.y); o.z = f2bf(v.z); o.w = f2bf(v.w);
  reinterpret_cast<short4*>(xb)[i] = o;
}

// ------------- weight transpose fp32 -> bf16 : dst[n][k] = src[k][n] -------------
__global__ __launch_bounds__(256) void k_tw(const float* __restrict__ wq,
                                            const float* __restrict__ wk,
                                            const float* __restrict__ wv,
                                            const float* __restrict__ wo,
                                            short* __restrict__ wqkvT,
                                            short* __restrict__ woT) {
  __shared__ float t[32][33];
  int wi = blockIdx.z;
  const float* src = (wi == 0) ? wq : (wi == 1) ? wk : (wi == 2) ? wv : wo;
  short* dst = (wi < 3) ? (wqkvT + wi * 1024 * 1024) : woT;
  int n0 = blockIdx.x * 32, k0 = blockIdx.y * 32;
  int tx = threadIdx.x, ty = threadIdx.y;
#pragma unroll
  for (int i = 0; i < 4; i++)
    t[ty + i * 8][tx] = src[(k0 + ty + i * 8) * 1024 + n0 + tx];
  __syncthreads();
#pragma unroll
  for (int i = 0; i < 4; i++)
    dst[(n0 + ty + i * 8) * 1024 + k0 + tx] = f2bf(t[tx][ty + i * 8]);
}

// ------------- GEMM: C[M,N] = A[M,K] * BT[N,K]^T (+bias)  -------------
// MODE 0: A=x_bf16 [4096,1024], BT=wqkvT [3072,1024];
//         bn 0..7 -> Q (B,H,L,64) scaled; bn 8..15 -> K (B,H,L,64);
//         bn 16..23 -> V^T (B,H,64,L) via LDS transpose (coalesced writes)
// MODE 1: A=ctx [4096,1024],    BT=woT [1024,1024];   out fp32 [4096,1024] + bo
template <int MODE>
__global__ __launch_bounds__(256) void k_gemm(
    const short* __restrict__ A, const short* __restrict__ BT,
    const float* __restrict__ b0, const float* __restrict__ b1,
    const float* __restrict__ b2, short* __restrict__ Qo,
    short* __restrict__ Ko, short* __restrict__ VTo,
    float* __restrict__ outF) {
  constexpr int K = 1024;
  __shared__ short As[128 * 64], Bs[128 * 64];
  __shared__ short SL[64 * 132];  // V^T transpose staging (MODE 0 only)
  const int tid = threadIdx.x;
  const int w = tid >> 6, lane = tid & 63;
  const int wr = w >> 1, wc = w & 1;
  const int bm = blockIdx.y, bn = blockIdx.x;
  const int lr = lane & 15, lg = lane >> 4;

  // staging: thread t covers LDS linear bytes i*4096 + t*16 (row = i*32 + t/8)
  // source column pre-swizzled so swizzled ds_reads see logical data
  const int rA = tid >> 3;                              // 0..31
  const int cbs = ((tid & 7) * 16) ^ ((rA & 7) << 4);   // swizzled byte col
  const short* pA[4];
  const short* pB[4];
#pragma unroll
  for (int i = 0; i < 4; i++) {
    pA[i] = A + (size_t)(bm * 128 + rA + i * 32) * K + (cbs >> 1);
    pB[i] = BT + (size_t)(bn * 128 + rA + i * 32) * K + (cbs >> 1);
  }

  v4f acc[4][4] = {};
  for (int kt = 0; kt < K / 64; ++kt) {
#pragma unroll
    for (int i = 0; i < 4; i++) {
      GLDS16(pA[i] + kt * 64, As + i * 2048 + w * 512);
      GLDS16(pB[i] + kt * 64, Bs + i * 2048 + w * 512);
    }
    __syncthreads();
#pragma unroll
    for (int ks = 0; ks < 2; ++ks) {
      v8s af[4], bf[4];
#pragma unroll
      for (int mf = 0; mf < 4; mf++) {
        int R = wr * 64 + mf * 16 + lr;
        int byo = (R * 128 + ks * 64 + lg * 16) ^ ((R & 7) << 4);
        af[mf] = *reinterpret_cast<const v8s*>(
            reinterpret_cast<const char*>(As) + byo);
      }
#pragma unroll
      for (int nf = 0; nf < 4; nf++) {
        int R = wc * 64 + nf * 16 + lr;
        int byo = (R * 128 + ks * 64 + lg * 16) ^ ((R & 7) << 4);
        bf[nf] = *reinterpret_cast<const v8s*>(
            reinterpret_cast<const char*>(Bs) + byo);
      }
      __builtin_amdgcn_s_setprio(1);
#pragma unroll
      for (int mf = 0; mf < 4; mf++)
#pragma unroll
        for (int nf = 0; nf < 4; nf++)
          acc[mf][nf] = mfma16(af[mf], bf[nf], acc[mf][nf]);
      __builtin_amdgcn_s_setprio(0);
    }
    __syncthreads();
  }

  if constexpr (MODE == 0) {
    if (bn < 16) {  // Q or K: near-coalesced 32B-chunk scatter
#pragma unroll
      for (int mf = 0; mf < 4; mf++) {
#pragma unroll
        for (int nf = 0; nf < 4; nf++) {
#pragma unroll
          for (int r = 0; r < 4; r++) {
            int mrow = bm * 128 + wr * 64 + mf * 16 + lg * 4 + r;
            int ncol = bn * 128 + wc * 64 + nf * 16 + lr;
            int which = ncol >> 10, d = ncol & 1023;
            float v = acc[mf][nf][r] + ((which == 0) ? b0[d] : b1[d]);
            int h = d >> 6, dh = d & 63;
            int bb = mrow >> 11, lp = mrow & 2047;
            if (which == 0)
              Qo[((size_t)(bb * 16 + h) * 2048 + lp) * 64 + dh] =
                  f2bf(v * 0.125f);  // fold 1/sqrt(Dh) into Q
            else
              Ko[((size_t)(bb * 16 + h) * 2048 + lp) * 64 + dh] = f2bf(v);
          }
        }
      }
    } else {  // V: transpose 128x128 C-tile through LDS, write VT coalesced
      const int bb = bm >> 4;
      const int lp0 = (bm & 15) * 128;
#pragma unroll
      for (int hh = 0; hh < 2; ++hh) {
        if (wc == hh) {
#pragma unroll
          for (int mf = 0; mf < 4; mf++)
#pragma unroll
            for (int nf = 0; nf < 4; nf++)
#pragma unroll
              for (int r = 0; r < 4; r++) {
                int mrow_l = wr * 64 + mf * 16 + lg * 4 + r;  // 0..127 (l)
                int ncol_l = nf * 16 + lr;                    // 0..63 (dv)
                int d = (bn - 16) * 128 + hh * 64 + ncol_l;   // 0..1023
                SL[ncol_l * 132 + mrow_l] = f2bf(acc[mf][nf][r] + b2[d]);
              }
        }
        __syncthreads();
        int h = (bn - 16) * 2 + hh;
        int row = tid >> 2;  // dv 0..63
#pragma unroll
        for (int q = 0; q < 4; q++) {
          int col = ((tid & 3) + q * 4) * 8;  // 4 consecutive 16B chunks
          *reinterpret_cast<v8s*>(
              VTo + ((size_t)(bb * 16 + h) * 64 + row) * 2048 + lp0 + col) =
              *reinterpret_cast<const v8s*>(SL + row * 132 + col);
        }
        __syncthreads();
      }
    }
  } else {
#pragma unroll
    for (int mf = 0; mf < 4; mf++)
#pragma unroll
      for (int nf = 0; nf < 4; nf++)
#pragma unroll
        for (int r = 0; r < 4; r++) {
          int mrow = bm * 128 + wr * 64 + mf * 16 + lg * 4 + r;
          int ncol = bn * 128 + wc * 64 + nf * 16 + lr;
          outF[(size_t)mrow * 1024 + ncol] = acc[mf][nf][r] + b0[ncol];
        }
  }
}

// ------------- causal flash attention -------------
// QBLK=128 (4 waves x 32 q-rows, 2 mf-tiles each), KV tiles of 64,
// double-buffered global_load_lds staging with XOR-swizzled layout.
__global__ __launch_bounds__(256) void k_flash(const short* __restrict__ Qg,
                                               const short* __restrict__ Kg,
                                               const short* __restrict__ VTg,
                                               short* __restrict__ ctx) {
  __shared__ short Kl[2][64 * 64], Vl[2][64 * 64];
  __shared__ short Pl[4][32 * 76];
  const int tid = threadIdx.x, w = tid >> 6, lane = tid & 63;
  const int lr = lane & 15, lg = lane >> 4;
  const int qt = 15 - (int)blockIdx.x;  // long blocks dispatch first
  const int bh = blockIdx.y;

  v8s q[2][2];
#pragma unroll
  for (int mf = 0; mf < 2; mf++) {
    const size_t qr = (size_t)bh * 2048 + qt * 128 + w * 32 + mf * 16 + lr;
    q[mf][0] = *reinterpret_cast<const v8s*>(Qg + qr * 64 + lg * 8);
    q[mf][1] = *reinterpret_cast<const v8s*>(Qg + qr * 64 + 32 + lg * 8);
  }

  float m_r[2][4], l_r[2][4];
  v4f o_[2][4] = {};
#pragma unroll
  for (int mf = 0; mf < 2; mf++)
#pragma unroll
    for (int r = 0; r < 4; r++) { m_r[mf][r] = -1e30f; l_r[mf][r] = 0.f; }

  const int rA = tid >> 3;                          // 0..31
  const int cs8 = ((tid & 7) ^ (rA & 7)) * 8;       // swizzled col (shorts)
  const short* kb = Kg + (size_t)bh * 2048 * 64;
  const short* vb = VTg + (size_t)bh * 64 * 2048;

  const int nt = 2 * qt + 2;
  int c = 0;
#define STAGE(kt_, cc_)                                                       \
  {                                                                           \
    _Pragma("unroll") for (int i = 0; i < 2; i++) {                           \
      GLDS16(kb + (size_t)((kt_)*64 + rA + i * 32) * 64 + cs8,                \
             &Kl[cc_][i * 2048 + w * 512]);                                   \
      GLDS16(vb + (size_t)(rA + i * 32) * 2048 + (kt_)*64 + cs8,              \
             &Vl[cc_][i * 2048 + w * 512]);                                   \
    }                                                                         \
  }
  STAGE(0, 0);

  for (int kt = 0; kt < nt; ++kt) {
    __syncthreads();  // drains vmcnt -> buf c ready
    if (kt + 1 < nt) STAGE(kt + 1, c ^ 1);

    v4f s[2][4] = {};
    __builtin_amdgcn_s_setprio(1);
#pragma unroll
    for (int nf = 0; nf < 4; nf++) {
      const int R = nf * 16 + lr;
      const char* rowp = reinterpret_cast<const char*>(Kl[c]) + R * 128;
      v8s k0 = *reinterpret_cast<const v8s*>(rowp + ((lg * 16) ^ ((R & 7) << 4)));
      v8s k1 = *reinterpret_cast<const v8s*>(rowp + ((64 + lg * 16) ^ ((R & 7) << 4)));
#pragma unroll
      for (int mf = 0; mf < 2; mf++) {
        s[mf][nf] = mfma16(q[mf][0], k0, s[mf][nf]);
        s[mf][nf] = mfma16(q[mf][1], k1, s[mf][nf]);
      }
    }
    __builtin_amdgcn_s_setprio(0);

    if (kt >= 2 * qt) {  // diagonal region: elementwise causal mask
#pragma unroll
      for (int mf = 0; mf < 2; mf++)
#pragma unroll
        for (int nf = 0; nf < 4; nf++)
#pragma unroll
          for (int r = 0; r < 4; r++) {
            int key = kt * 64 + nf * 16 + lr;
            int qq = qt * 128 + w * 32 + mf * 16 + lg * 4 + r;
            if (key > qq) s[mf][nf][r] = -1e30f;
          }
    }

#pragma unroll
    for (int mf = 0; mf < 2; mf++) {
      float pm[4];
#pragma unroll
      for (int r = 0; r < 4; r++)
        pm[r] = fmaxf(fmaxf(s[mf][0][r], s[mf][1][r]),
                      fmaxf(s[mf][2][r], s[mf][3][r]));
#pragma unroll
      for (int off = 1; off < 16; off <<= 1)
#pragma unroll
        for (int r = 0; r < 4; r++)
          pm[r] = fmaxf(pm[r], __shfl_xor(pm[r], off, 64));

      float alpha[4], rs[4], p[4][4];
#pragma unroll
      for (int r = 0; r < 4; r++) {
        float mn = fmaxf(m_r[mf][r], pm[r]);
        alpha[r] = __expf(m_r[mf][r] - mn);
        m_r[mf][r] = mn;
        rs[r] = 0.f;
      }
#pragma unroll
      for (int nf = 0; nf < 4; nf++)
#pragma unroll
        for (int r = 0; r < 4; r++) {
          p[nf][r] = __expf(s[mf][nf][r] - m_r[mf][r]);
          rs[r] += p[nf][r];
        }
#pragma unroll
      for (int off = 1; off < 16; off <<= 1)
#pragma unroll
        for (int r = 0; r < 4; r++) rs[r] += __shfl_xor(rs[r], off, 64);
#pragma unroll
      for (int r = 0; r < 4; r++) l_r[mf][r] = l_r[mf][r] * alpha[r] + rs[r];
#pragma unroll
      for (int nf = 0; nf < 4; nf++)
#pragma unroll
        for (int r = 0; r < 4; r++) o_[mf][nf][r] *= alpha[r];
#pragma unroll
      for (int nf = 0; nf < 4; nf++)
#pragma unroll
        for (int r = 0; r < 4; r++)
          Pl[w][(mf * 16 + lg * 4 + r) * 76 + nf * 16 + lr] = f2bf(p[nf][r]);
    }

    __builtin_amdgcn_s_setprio(1);
#pragma unroll
    for (int mf = 0; mf < 2; mf++)
#pragma unroll
      for (int ks = 0; ks < 2; ks++) {
        v8s af = *reinterpret_cast<const v8s*>(
            &Pl[w][(mf * 16 + lr) * 76 + ks * 32 + lg * 8]);
#pragma unroll
        for (int nf = 0; nf < 4; nf++) {
          const int R = nf * 16 + lr;
          v8s bv = *reinterpret_cast<const v8s*>(
              reinterpret_cast<const char*>(Vl[c]) + R * 128 +
              ((ks * 64 + lg * 16) ^ ((R & 7) << 4)));
          o_[mf][nf] = mfma16(af, bv, o_[mf][nf]);
        }
      }
    __builtin_amdgcn_s_setprio(0);
    c ^= 1;
  }

  const int h = bh & 15, bb = bh >> 4;
#pragma unroll
  for (int mf = 0; mf < 2; mf++)
#pragma unroll
    for (int r = 0; r < 4; r++) {
      float inv = 1.0f / l_r[mf][r];
      int qq = qt * 128 + w * 32 + mf * 16 + lg * 4 + r;
#pragma unroll
      for (int nf = 0; nf < 4; nf++)
        ctx[((size_t)(bb * 2048 + qq)) * 1024 + h * 64 + nf * 16 + lr] =
            f2bf(o_[mf][nf][r] * inv);
    }
}

extern "C" void kernel_launch(void* const* d_in, const int* in_sizes, int n_in,
                              void* d_out, int out_size, void* d_ws,
                              size_t ws_size, hipStream_t stream) {
  (void)in_sizes; (void)n_in; (void)out_size; (void)ws_size;
  const float* x = (const float*)d_in[0];
  // d_in[1] = causal_mask (implemented analytically)
  const float* wq = (const float*)d_in[2];
  const float* bq = (const float*)d_in[3];
  const float* wk = (const float*)d_in[4];
  const float* bk = (const float*)d_in[5];
  const float* wv = (const float*)d_in[6];
  const float* bv = (const float*)d_in[7];
  const float* wo = (const float*)d_in[8];
  const float* bo = (const float*)d_in[9];

  char* ws = (char*)d_ws;
  short* xb = (short*)(ws);                      // 8 MB (reused as ctx later)
  short* wqkvT = (short*)(ws + (8u << 20));      // 6 MB
  short* woT = (short*)(ws + (14u << 20));       // 2 MB
  short* Qb = (short*)(ws + (16u << 20));        // 8 MB
  short* Kb = (short*)(ws + (24u << 20));        // 8 MB
  short* VTb = (short*)(ws + (32u << 20));       // 8 MB
  short* ctx = xb;                               // alias: xb dead after QKV GEMM
  float* out = (float*)d_out;

  k_cvt<<<4096, 256, 0, stream>>>(x, xb);
  k_tw<<<dim3(32, 32, 4), dim3(32, 8), 0, stream>>>(wq, wk, wv, wo, wqkvT, woT);
  k_gemm<0><<<dim3(24, 32), 256, 0, stream>>>(xb, wqkvT, bq, bk, bv, Qb, Kb,
                                              VTb, nullptr);
  k_flash<<<dim3(16, 32), 256, 0, stream>>>(Qb, Kb, VTb, ctx);
  k_gemm<1><<<dim3(8, 32), 256, 0, stream>>>(ctx, woT, bo, nullptr, nullptr,
                                             nullptr, nullptr, nullptr, out);
}

// Round 4
// 232.700 us; speedup vs baseline: 1.3057x; 1.1823x over previous
//
#include <hip/hip_runtime.h>

// MultiHeadAttention fused pipeline for MI355X (gfx950)
// B=2, L=2048, D=1024, H=16, Dh=64.  fp32 in/out, bf16 MFMA compute.

typedef short v8s __attribute__((ext_vector_type(8)));
typedef __bf16 v8bf __attribute__((ext_vector_type(8)));
typedef float v4f __attribute__((ext_vector_type(4)));
typedef float v16f __attribute__((ext_vector_type(16)));
typedef unsigned int uint;

#define DEV static __device__ __forceinline__

DEV short f2bf(float f) {  // RNE float->bf16 (no NaN inputs here)
  unsigned u = __builtin_bit_cast(unsigned, f);
  u += 0x7FFFu + ((u >> 16) & 1u);
  return (short)(u >> 16);
}

DEV uint pack2(float lo, float hi) {  // 2 f32 -> packed 2xbf16 word
  return (uint)(unsigned short)f2bf(lo) | ((uint)(unsigned short)f2bf(hi) << 16);
}

DEV v4f mfma16(v8s a, v8s b, v4f c) {
  return __builtin_amdgcn_mfma_f32_16x16x32_bf16(
      __builtin_bit_cast(v8bf, a), __builtin_bit_cast(v8bf, b), c, 0, 0, 0);
}

DEV v16f mfma32(v8s a, v8s b, v16f c) {
  return __builtin_amdgcn_mfma_f32_32x32x16_bf16(
      __builtin_bit_cast(v8bf, a), __builtin_bit_cast(v8bf, b), c, 0, 0, 0);
}

#define GLDS16(g, l)                                                         \
  __builtin_amdgcn_global_load_lds(                                          \
      (__attribute__((address_space(1))) void*)(g),                          \
      (__attribute__((address_space(3))) void*)(l), 16, 0, 0)

// ---------------- x -> bf16 ----------------
__global__ __launch_bounds__(256) void k_cvt(const float* __restrict__ x,
                                             short* __restrict__ xb) {
  int i = blockIdx.x * 256 + threadIdx.x;
  float4 v = reinterpret_cast<const float4*>(x)[i];
  short4 o;
  o.x = f2bf(v.x); o.y = f2bf(v.y); o.z = f2bf(v.z); o.w = f2bf(v.w);
  reinterpret_cast<short4*>(xb)[i] = o;
}

// ------------- weight transpose fp32 -> bf16 : dst[n][k] = src[k][n] -------------
__global__ __launch_bounds__(256) void k_tw(const float* __restrict__ wq,
                                            const float* __restrict__ wk,
                                            const float* __restrict__ wv,
                                            const float* __restrict__ wo,
                                            short* __restrict__ wqkvT,
                                            short* __restrict__ woT) {
  __shared__ float t[32][33];
  int wi = blockIdx.z;
  const float* src = (wi == 0) ? wq : (wi == 1) ? wk : (wi == 2) ? wv : wo;
  short* dst = (wi < 3) ? (wqkvT + wi * 1024 * 1024) : woT;
  int n0 = blockIdx.x * 32, k0 = blockIdx.y * 32;
  int tx = threadIdx.x, ty = threadIdx.y;
#pragma unroll
  for (int i = 0; i < 4; i++)
    t[ty + i * 8][tx] = src[(k0 + ty + i * 8) * 1024 + n0 + tx];
  __syncthreads();
#pragma unroll
  for (int i = 0; i < 4; i++)
    dst[(n0 + ty + i * 8) * 1024 + k0 + tx] = f2bf(t[tx][ty + i * 8]);
}

// ------------- GEMM: C[M,N] = A[M,K] * BT[N,K]^T (+bias)  -------------
// MODE 0: A=x_bf16 [4096,1024], BT=wqkvT [3072,1024];
//         bn 0..7 -> Q (B,H,L,64) scaled; bn 8..15 -> K (B,H,L,64);
//         bn 16..23 -> V^T (B,H,64,L) via LDS transpose (coalesced writes)
// MODE 1: A=ctx [4096,1024],    BT=woT [1024,1024];   out fp32 [4096,1024] + bo
template <int MODE>
__global__ __launch_bounds__(256) void k_gemm(
    const short* __restrict__ A, const short* __restrict__ BT,
    const float* __restrict__ b0, const float* __restrict__ b1,
    const float* __restrict__ b2, short* __restrict__ Qo,
    short* __restrict__ Ko, short* __restrict__ VTo,
    float* __restrict__ outF) {
  constexpr int K = 1024;
  __shared__ short As[128 * 64], Bs[128 * 64];
  __shared__ short SL[64 * 132];  // V^T transpose staging (MODE 0 only)
  const int tid = threadIdx.x;
  const int w = tid >> 6, lane = tid & 63;
  const int wr = w >> 1, wc = w & 1;
  const int bm = blockIdx.y, bn = blockIdx.x;
  const int lr = lane & 15, lg = lane >> 4;

  // staging: thread t covers LDS linear bytes i*4096 + t*16 (row = i*32 + t/8)
  // source column pre-swizzled so swizzled ds_reads see logical data
  const int rA = tid >> 3;                              // 0..31
  const int cbs = ((tid & 7) * 16) ^ ((rA & 7) << 4);   // swizzled byte col
  const short* pA[4];
  const short* pB[4];
#pragma unroll
  for (int i = 0; i < 4; i++) {
    pA[i] = A + (size_t)(bm * 128 + rA + i * 32) * K + (cbs >> 1);
    pB[i] = BT + (size_t)(bn * 128 + rA + i * 32) * K + (cbs >> 1);
  }

  v4f acc[4][4] = {};
  for (int kt = 0; kt < K / 64; ++kt) {
#pragma unroll
    for (int i = 0; i < 4; i++) {
      GLDS16(pA[i] + kt * 64, As + i * 2048 + w * 512);
      GLDS16(pB[i] + kt * 64, Bs + i * 2048 + w * 512);
    }
    __syncthreads();
#pragma unroll
    for (int ks = 0; ks < 2; ++ks) {
      v8s af[4], bf[4];
#pragma unroll
      for (int mf = 0; mf < 4; mf++) {
        int R = wr * 64 + mf * 16 + lr;
        int byo = (R * 128 + ks * 64 + lg * 16) ^ ((R & 7) << 4);
        af[mf] = *reinterpret_cast<const v8s*>(
            reinterpret_cast<const char*>(As) + byo);
      }
#pragma unroll
      for (int nf = 0; nf < 4; nf++) {
        int R = wc * 64 + nf * 16 + lr;
        int byo = (R * 128 + ks * 64 + lg * 16) ^ ((R & 7) << 4);
        bf[nf] = *reinterpret_cast<const v8s*>(
            reinterpret_cast<const char*>(Bs) + byo);
      }
      __builtin_amdgcn_s_setprio(1);
#pragma unroll
      for (int mf = 0; mf < 4; mf++)
#pragma unroll
        for (int nf = 0; nf < 4; nf++)
          acc[mf][nf] = mfma16(af[mf], bf[nf], acc[mf][nf]);
      __builtin_amdgcn_s_setprio(0);
    }
    __syncthreads();
  }

  if constexpr (MODE == 0) {
    if (bn < 16) {  // Q or K: near-coalesced 32B-chunk scatter
#pragma unroll
      for (int mf = 0; mf < 4; mf++) {
#pragma unroll
        for (int nf = 0; nf < 4; nf++) {
#pragma unroll
          for (int r = 0; r < 4; r++) {
            int mrow = bm * 128 + wr * 64 + mf * 16 + lg * 4 + r;
            int ncol = bn * 128 + wc * 64 + nf * 16 + lr;
            int which = ncol >> 10, d = ncol & 1023;
            float v = acc[mf][nf][r] + ((which == 0) ? b0[d] : b1[d]);
            int h = d >> 6, dh = d & 63;
            int bb = mrow >> 11, lp = mrow & 2047;
            if (which == 0)
              Qo[((size_t)(bb * 16 + h) * 2048 + lp) * 64 + dh] =
                  f2bf(v * 0.18033688011112043f);  // 1/sqrt(Dh) * log2(e)
            else
              Ko[((size_t)(bb * 16 + h) * 2048 + lp) * 64 + dh] = f2bf(v);
          }
        }
      }
    } else {  // V: transpose 128x128 C-tile through LDS, write VT coalesced
      const int bb = bm >> 4;
      const int lp0 = (bm & 15) * 128;
#pragma unroll
      for (int hh = 0; hh < 2; ++hh) {
        if (wc == hh) {
#pragma unroll
          for (int mf = 0; mf < 4; mf++)
#pragma unroll
            for (int nf = 0; nf < 4; nf++)
#pragma unroll
              for (int r = 0; r < 4; r++) {
                int mrow_l = wr * 64 + mf * 16 + lg * 4 + r;  // 0..127 (l)
                int ncol_l = nf * 16 + lr;                    // 0..63 (dv)
                int d = (bn - 16) * 128 + hh * 64 + ncol_l;   // 0..1023
                SL[ncol_l * 132 + mrow_l] = f2bf(acc[mf][nf][r] + b2[d]);
              }
        }
        __syncthreads();
        int h = (bn - 16) * 2 + hh;
        int row = tid >> 2;  // dv 0..63
#pragma unroll
        for (int q = 0; q < 4; q++) {
          int col = ((tid & 3) + q * 4) * 8;  // 4 consecutive 16B chunks
          *reinterpret_cast<v8s*>(
              VTo + ((size_t)(bb * 16 + h) * 64 + row) * 2048 + lp0 + col) =
              *reinterpret_cast<const v8s*>(SL + row * 132 + col);
        }
        __syncthreads();
      }
    }
  } else {
#pragma unroll
    for (int mf = 0; mf < 4; mf++)
#pragma unroll
      for (int nf = 0; nf < 4; nf++)
#pragma unroll
        for (int r = 0; r < 4; r++) {
          int mrow = bm * 128 + wr * 64 + mf * 16 + lg * 4 + r;
          int ncol = bn * 128 + wc * 64 + nf * 16 + lr;
          outF[(size_t)mrow * 1024 + ncol] = acc[mf][nf][r] + b0[ncol];
        }
  }
}

// ------------- causal flash attention (swapped-operand 32x32 structure) -----
// QBLK=128 (4 waves x 32 q-rows), KVBLK=64, double-buffered global_load_lds.
// S^T = mfma(K, Q): lane owns q = lane&31; keys spread over regs/half.
// O^T = mfma(V^T, P): P redistributed in-register via shfl_xor(32) + select.
__global__ __launch_bounds__(256) void k_flash(const short* __restrict__ Qg,
                                               const short* __restrict__ Kg,
                                               const short* __restrict__ VTg,
                                               short* __restrict__ ctx) {
  __shared__ short Kl[2][64 * 64], Vl[2][64 * 64];
  const int tid = threadIdx.x, w = tid >> 6, lane = tid & 63;
  const int l31 = lane & 31, hi = lane >> 5;
  const int y = blockIdx.y;
  const int bh = y;
  // complementary qt for co-resident blocks (id, id+256): uniform per-CU work
  const int qt = (y < 16) ? (15 - (int)blockIdx.x) : (int)blockIdx.x;
  const int q = qt * 128 + w * 32 + l31;  // this lane's q row (global in L)

  // Q fragments (b-operand): qf[dc] = Q[q][dc*16 + hi*8 .. +7]
  v8s qf[4];
  {
    const short* qrow = Qg + ((size_t)bh * 2048 + q) * 64 + hi * 8;
#pragma unroll
    for (int dc = 0; dc < 4; dc++)
      qf[dc] = *reinterpret_cast<const v8s*>(qrow + dc * 16);
  }

  float m = -1e30f, l = 0.f;
  v16f o0 = {}, o1 = {};  // O^T, d = df*32 + (r&3)+8*(r>>2)+4*hi, col q=l31

  const int rA = tid >> 3;                      // 0..31
  const int cs8 = ((tid & 7) ^ (rA & 7)) * 8;   // swizzled col (shorts)
  const short* kb = Kg + (size_t)bh * 2048 * 64;
  const short* vb = VTg + (size_t)bh * 64 * 2048;

  const int nt = 2 * qt + 2;
  int c = 0;
#define STAGE(kt_, cc_)                                                       \
  {                                                                           \
    _Pragma("unroll") for (int i = 0; i < 2; i++) {                           \
      GLDS16(kb + (size_t)((kt_)*64 + rA + i * 32) * 64 + cs8,                \
             &Kl[cc_][i * 2048 + w * 512]);                                   \
      GLDS16(vb + (size_t)(rA + i * 32) * 2048 + (kt_)*64 + cs8,              \
             &Vl[cc_][i * 2048 + w * 512]);                                   \
    }                                                                         \
  }
  STAGE(0, 0);

  const int rxor = (l31 & 7) << 4;
  const int rowb = l31 * 128;  // byte offset of row l31 (128B rows)

  for (int kt = 0; kt < nt; ++kt) {
    __syncthreads();  // drains vmcnt -> buf c ready
    if (kt + 1 < nt) STAGE(kt + 1, c ^ 1);

    // ---- QK^T (swapped): s0/s1 = S^T tiles for k = kt*64 + [0..31]/[32..63]
    v16f s0 = {}, s1 = {};
    const char* Klc = reinterpret_cast<const char*>(Kl[c]);
    __builtin_amdgcn_s_setprio(1);
#pragma unroll
    for (int dc = 0; dc < 4; dc++) {
      int cb = (dc * 32 + hi * 16) ^ rxor;
      v8s k0 = *reinterpret_cast<const v8s*>(Klc + rowb + cb);
      v8s k1 = *reinterpret_cast<const v8s*>(Klc + 4096 + rowb + cb);
      s0 = mfma32(k0, qf[dc], s0);
      s1 = mfma32(k1, qf[dc], s1);
    }
    __builtin_amdgcn_s_setprio(0);

    // ---- causal mask (diagonal tiles only)
    if (kt >= 2 * qt) {
      int kb0 = kt * 64 + 4 * hi;
#pragma unroll
      for (int r = 0; r < 16; r++) {
        int kv = kb0 + (r & 3) + 8 * (r >> 2);
        if (kv > q) s0[r] = -1e30f;
        if (kv + 32 > q) s1[r] = -1e30f;
      }
    }

    // ---- online softmax (log2 domain; defer-max THR=8)
    float pm = s0[0];
#pragma unroll
    for (int r = 1; r < 16; r++) pm = fmaxf(pm, s0[r]);
#pragma unroll
    for (int r = 0; r < 16; r++) pm = fmaxf(pm, s1[r]);
    pm = fmaxf(pm, __shfl_xor(pm, 32, 64));  // cross-half row max
    if (__any(pm - m > 8.0f)) {
      float mn = fmaxf(m, pm);
      float alpha = exp2f(m - mn);
      m = mn;
      l *= alpha;
#pragma unroll
      for (int r = 0; r < 16; r++) { o0[r] *= alpha; o1[r] *= alpha; }
    }
    float rs = 0.f;
#pragma unroll
    for (int r = 0; r < 16; r++) {
      s0[r] = exp2f(fminf(s0[r] - m, 126.0f));
      rs += s0[r];
    }
#pragma unroll
    for (int r = 0; r < 16; r++) {
      s1[r] = exp2f(fminf(s1[r] - m, 126.0f));
      rs += s1[r];
    }
    l += rs + __shfl_xor(rs, 32, 64);

    // ---- pack P to bf16 words: W[t] = (p[2t], p[2t+1]) — consecutive keys
    uint W0[8], W1[8];
#pragma unroll
    for (int t = 0; t < 8; t++) {
      W0[t] = pack2(s0[2 * t], s0[2 * t + 1]);
      W1[t] = pack2(s1[2 * t], s1[2 * t + 1]);
    }

    // ---- PV (swapped): O^T += mfma(VT-frag, P-frag) over 4 key-chunks of 16
    // B-frag words for chunk: hi=0 -> (S0,S1, partner S0, partner S1)
    //                         hi=1 -> (partner S2, partner S3, S2, S3)
    const char* Vlc = reinterpret_cast<const char*>(Vl[c]);
#pragma unroll
    for (int kc = 0; kc < 4; kc++) {
      uint S0, S1, S2, S3;
      if (kc == 0) { S0 = W0[0]; S1 = W0[1]; S2 = W0[2]; S3 = W0[3]; }
      else if (kc == 1) { S0 = W0[4]; S1 = W0[5]; S2 = W0[6]; S3 = W0[7]; }
      else if (kc == 2) { S0 = W1[0]; S1 = W1[1]; S2 = W1[2]; S3 = W1[3]; }
      else { S0 = W1[4]; S1 = W1[5]; S2 = W1[6]; S3 = W1[7]; }
      uint x0 = __shfl_xor(hi ? S0 : S2, 32, 64);
      uint x1 = __shfl_xor(hi ? S1 : S3, 32, 64);
      uint u0 = hi ? x0 : S0;
      uint u1 = hi ? x1 : S1;
      uint u2 = hi ? S2 : x0;
      uint u3 = hi ? S3 : x1;
      uint4 uf = {u0, u1, u2, u3};
      v8s pf = __builtin_bit_cast(v8s, uf);
      int cb = (kc * 32 + hi * 16) ^ rxor;
      v8s v0 = *reinterpret_cast<const v8s*>(Vlc + rowb + cb);
      v8s v1 = *reinterpret_cast<const v8s*>(Vlc + 4096 + rowb + cb);
      __builtin_amdgcn_s_setprio(1);
      o0 = mfma32(v0, pf, o0);
      o1 = mfma32(v1, pf, o1);
      __builtin_amdgcn_s_setprio(0);
    }
    c ^= 1;
  }

  // ---- epilogue: ctx[bb*2048 + q][h*64 + d] = O^T[d][q] / l
  const int h = bh & 15, bb = bh >> 4;
  float inv = 1.0f / l;
  short* orow = ctx + ((size_t)(bb * 2048 + q)) * 1024 + h * 64;
#pragma unroll
  for (int df = 0; df < 2; df++) {
#pragma unroll
    for (int g = 0; g < 4; g++) {
      short4 st;
      const v16f& o = df ? o1 : o0;
      st.x = f2bf(o[g * 4 + 0] * inv);
      st.y = f2bf(o[g * 4 + 1] * inv);
      st.z = f2bf(o[g * 4 + 2] * inv);
      st.w = f2bf(o[g * 4 + 3] * inv);
      *reinterpret_cast<short4*>(orow + df * 32 + 8 * g + 4 * hi) = st;
    }
  }
}

extern "C" void kernel_launch(void* const* d_in, const int* in_sizes, int n_in,
                              void* d_out, int out_size, void* d_ws,
                              size_t ws_size, hipStream_t stream) {
  (void)in_sizes; (void)n_in; (void)out_size; (void)ws_size;
  const float* x = (const float*)d_in[0];
  // d_in[1] = causal_mask (implemented analytically)
  const float* wq = (const float*)d_in[2];
  const float* bq = (const float*)d_in[3];
  const float* wk = (const float*)d_in[4];
  const float* bk = (const float*)d_in[5];
  const float* wv = (const float*)d_in[6];
  const float* bv = (const float*)d_in[7];
  const float* wo = (const float*)d_in[8];
  const float* bo = (const float*)d_in[9];

  char* ws = (char*)d_ws;
  short* xb = (short*)(ws);                      // 8 MB (reused as ctx later)
  short* wqkvT = (short*)(ws + (8u << 20));      // 6 MB
  short* woT = (short*)(ws + (14u << 20));       // 2 MB
  short* Qb = (short*)(ws + (16u << 20));        // 8 MB
  short* Kb = (short*)(ws + (24u << 20));        // 8 MB
  short* VTb = (short*)(ws + (32u << 20));       // 8 MB
  short* ctx = xb;                               // alias: xb dead after QKV GEMM
  float* out = (float*)d_out;

  k_cvt<<<4096, 256, 0, stream>>>(x, xb);
  k_tw<<<dim3(32, 32, 4), dim3(32, 8), 0, stream>>>(wq, wk, wv, wo, wqkvT, woT);
  k_gemm<0><<<dim3(24, 32), 256, 0, stream>>>(xb, wqkvT, bq, bk, bv, Qb, Kb,
                                              VTb, nullptr);
  k_flash<<<dim3(16, 32), 256, 0, stream>>>(Qb, Kb, VTb, ctx);
  k_gemm<1><<<dim3(8, 32), 256, 0, stream>>>(ctx, woT, bo, nullptr, nullptr,
                                             nullptr, nullptr, nullptr, out);
}

// Round 6
// 212.678 us; speedup vs baseline: 1.4286x; 1.0941x over previous
//
#include <hip/hip_runtime.h>

// MultiHeadAttention fused pipeline for MI355X (gfx950)
// B=2, L=2048, D=1024, H=16, Dh=64.  fp32 in/out, bf16 MFMA compute.

typedef short v8s __attribute__((ext_vector_type(8)));
typedef __bf16 v8bf __attribute__((ext_vector_type(8)));
typedef float v4f __attribute__((ext_vector_type(4)));
typedef float v16f __attribute__((ext_vector_type(16)));
typedef unsigned int uint;

#define DEV static __device__ __forceinline__

DEV short f2bf(float f) {  // RNE float->bf16 (no NaN inputs here)
  unsigned u = __builtin_bit_cast(unsigned, f);
  u += 0x7FFFu + ((u >> 16) & 1u);
  return (short)(u >> 16);
}

DEV uint pack2(float lo, float hi) {  // 2 f32 -> packed 2xbf16 word
  return (uint)(unsigned short)f2bf(lo) | ((uint)(unsigned short)f2bf(hi) << 16);
}

DEV v4f mfma16(v8s a, v8s b, v4f c) {
  return __builtin_amdgcn_mfma_f32_16x16x32_bf16(
      __builtin_bit_cast(v8bf, a), __builtin_bit_cast(v8bf, b), c, 0, 0, 0);
}

DEV v16f mfma32(v8s a, v8s b, v16f c) {
  return __builtin_amdgcn_mfma_f32_32x32x16_bf16(
      __builtin_bit_cast(v8bf, a), __builtin_bit_cast(v8bf, b), c, 0, 0, 0);
}

#define GLDS16(g, l)                                                         \
  __builtin_amdgcn_global_load_lds(                                          \
      (__attribute__((address_space(1))) void*)(g),                          \
      (__attribute__((address_space(3))) void*)(l), 16, 0, 0)

// ---------------- x -> bf16 ----------------
__global__ __launch_bounds__(256) void k_cvt(const float* __restrict__ x,
                                             short* __restrict__ xb) {
  int i = blockIdx.x * 256 + threadIdx.x;
  float4 v = reinterpret_cast<const float4*>(x)[i];
  short4 o;
  o.x = f2bf(v.x); o.y = f2bf(v.y); o.z = f2bf(v.z); o.w = f2bf(v.w);
  reinterpret_cast<short4*>(xb)[i] = o;
}

// ------------- weight transpose fp32 -> bf16 : dst[n][k] = src[k][n] -------------
__global__ __launch_bounds__(256) void k_tw(const float* __restrict__ wq,
                                            const float* __restrict__ wk,
                                            const float* __restrict__ wv,
                                            const float* __restrict__ wo,
                                            short* __restrict__ wqkvT,
                                            short* __restrict__ woT) {
  __shared__ float t[32][33];
  int wi = blockIdx.z;
  const float* src = (wi == 0) ? wq : (wi == 1) ? wk : (wi == 2) ? wv : wo;
  short* dst = (wi < 3) ? (wqkvT + wi * 1024 * 1024) : woT;
  int n0 = blockIdx.x * 32, k0 = blockIdx.y * 32;
  int tx = threadIdx.x, ty = threadIdx.y;
#pragma unroll
  for (int i = 0; i < 4; i++)
    t[ty + i * 8][tx] = src[(k0 + ty + i * 8) * 1024 + n0 + tx];
  __syncthreads();
#pragma unroll
  for (int i = 0; i < 4; i++)
    dst[(n0 + ty + i * 8) * 1024 + k0 + tx] = f2bf(t[tx][ty + i * 8]);
}

// ------------- GEMM: C[M,N] = A[M,K] * BT[N,K]^T (+bias)  -------------
// MODE 0: A=x_bf16 [4096,1024], BT=wqkvT [3072,1024];
//         bn 0..7 -> Q (B,H,L,64) scaled; bn 8..15 -> K (B,H,L,64);
//         bn 16..23 -> V^T (B,H,64,L) via LDS transpose (coalesced writes)
// MODE 1: A=ctx [4096,1024],    BT=woT [1024,1024];   out fp32 [4096,1024] + bo
template <int MODE>
__global__ __launch_bounds__(256) void k_gemm(
    const short* __restrict__ A, const short* __restrict__ BT,
    const float* __restrict__ b0, const float* __restrict__ b1,
    const float* __restrict__ b2, short* __restrict__ Qo,
    short* __restrict__ Ko, short* __restrict__ VTo,
    float* __restrict__ outF) {
  constexpr int K = 1024;
  __shared__ short As[128 * 64], Bs[128 * 64];
  __shared__ short SL[64 * 132];  // V^T transpose staging (MODE 0 only)
  const int tid = threadIdx.x;
  const int w = tid >> 6, lane = tid & 63;
  const int wr = w >> 1, wc = w & 1;
  const int bm = blockIdx.y, bn = blockIdx.x;
  const int lr = lane & 15, lg = lane >> 4;

  // staging: thread t covers LDS linear bytes i*4096 + t*16 (row = i*32 + t/8)
  // source column pre-swizzled so swizzled ds_reads see logical data
  const int rA = tid >> 3;                              // 0..31
  const int cbs = ((tid & 7) * 16) ^ ((rA & 7) << 4);   // swizzled byte col
  const short* pA[4];
  const short* pB[4];
#pragma unroll
  for (int i = 0; i < 4; i++) {
    pA[i] = A + (size_t)(bm * 128 + rA + i * 32) * K + (cbs >> 1);
    pB[i] = BT + (size_t)(bn * 128 + rA + i * 32) * K + (cbs >> 1);
  }

  v4f acc[4][4] = {};
  for (int kt = 0; kt < K / 64; ++kt) {
#pragma unroll
    for (int i = 0; i < 4; i++) {
      GLDS16(pA[i] + kt * 64, As + i * 2048 + w * 512);
      GLDS16(pB[i] + kt * 64, Bs + i * 2048 + w * 512);
    }
    __syncthreads();
#pragma unroll
    for (int ks = 0; ks < 2; ++ks) {
      v8s af[4], bf[4];
#pragma unroll
      for (int mf = 0; mf < 4; mf++) {
        int R = wr * 64 + mf * 16 + lr;
        int byo = (R * 128 + ks * 64 + lg * 16) ^ ((R & 7) << 4);
        af[mf] = *reinterpret_cast<const v8s*>(
            reinterpret_cast<const char*>(As) + byo);
      }
#pragma unroll
      for (int nf = 0; nf < 4; nf++) {
        int R = wc * 64 + nf * 16 + lr;
        int byo = (R * 128 + ks * 64 + lg * 16) ^ ((R & 7) << 4);
        bf[nf] = *reinterpret_cast<const v8s*>(
            reinterpret_cast<const char*>(Bs) + byo);
      }
      __builtin_amdgcn_s_setprio(1);
#pragma unroll
      for (int mf = 0; mf < 4; mf++)
#pragma unroll
        for (int nf = 0; nf < 4; nf++)
          acc[mf][nf] = mfma16(af[mf], bf[nf], acc[mf][nf]);
      __builtin_amdgcn_s_setprio(0);
    }
    __syncthreads();
  }

  if constexpr (MODE == 0) {
    if (bn < 16) {  // Q or K: near-coalesced 32B-chunk scatter
#pragma unroll
      for (int mf = 0; mf < 4; mf++) {
#pragma unroll
        for (int nf = 0; nf < 4; nf++) {
#pragma unroll
          for (int r = 0; r < 4; r++) {
            int mrow = bm * 128 + wr * 64 + mf * 16 + lg * 4 + r;
            int ncol = bn * 128 + wc * 64 + nf * 16 + lr;
            int which = ncol >> 10, d = ncol & 1023;
            float v = acc[mf][nf][r] + ((which == 0) ? b0[d] : b1[d]);
            int h = d >> 6, dh = d & 63;
            int bb = mrow >> 11, lp = mrow & 2047;
            if (which == 0)
              Qo[((size_t)(bb * 16 + h) * 2048 + lp) * 64 + dh] =
                  f2bf(v * 0.18033688011112043f);  // 1/sqrt(Dh) * log2(e)
            else
              Ko[((size_t)(bb * 16 + h) * 2048 + lp) * 64 + dh] = f2bf(v);
          }
        }
      }
    } else {  // V: transpose 128x128 C-tile through LDS, write VT coalesced
      const int bb = bm >> 4;
      const int lp0 = (bm & 15) * 128;
#pragma unroll
      for (int hh = 0; hh < 2; ++hh) {
        if (wc == hh) {
#pragma unroll
          for (int mf = 0; mf < 4; mf++)
#pragma unroll
            for (int nf = 0; nf < 4; nf++)
#pragma unroll
              for (int r = 0; r < 4; r++) {
                int mrow_l = wr * 64 + mf * 16 + lg * 4 + r;  // 0..127 (l)
                int ncol_l = nf * 16 + lr;                    // 0..63 (dv)
                int d = (bn - 16) * 128 + hh * 64 + ncol_l;   // 0..1023
                SL[ncol_l * 132 + mrow_l] = f2bf(acc[mf][nf][r] + b2[d]);
              }
        }
        __syncthreads();
        int h = (bn - 16) * 2 + hh;
        int row = tid >> 2;  // dv 0..63
#pragma unroll
        for (int q = 0; q < 4; q++) {
          int col = ((tid & 3) + q * 4) * 8;  // 4 consecutive 16B chunks
          *reinterpret_cast<v8s*>(
              VTo + ((size_t)(bb * 16 + h) * 64 + row) * 2048 + lp0 + col) =
              *reinterpret_cast<const v8s*>(SL + row * 132 + col);
        }
        __syncthreads();
      }
    }
  } else {
#pragma unroll
    for (int mf = 0; mf < 4; mf++)
#pragma unroll
      for (int nf = 0; nf < 4; nf++)
#pragma unroll
        for (int r = 0; r < 4; r++) {
          int mrow = bm * 128 + wr * 64 + mf * 16 + lg * 4 + r;
          int ncol = bn * 128 + wc * 64 + nf * 16 + lr;
          outF[(size_t)mrow * 1024 + ncol] = acc[mf][nf][r] + b0[ncol];
        }
  }
}

// ------------- causal flash attention (swapped-operand, KVBLK=128) ----------
// QBLK=128 (4 waves x 32 q-rows), KVBLK=128, double-buffered global_load_lds.
// grid (bh=32, y=16): id%8 = bh%8 -> all q-blocks of a head on one XCD (L2).
// S^T = mfma(K, Q): lane owns q = lane&31; O^T = mfma(V^T, P), P exchanged
// in-register via shfl_xor(32) + select (round-4-verified 4-word pattern).
__global__ __launch_bounds__(256) void k_flash(const short* __restrict__ Qg,
                                               const short* __restrict__ Kg,
                                               const short* __restrict__ VTg,
                                               short* __restrict__ ctx) {
  __shared__ short Kl[2][128 * 64];  // [key 128][d 64] 128B rows, swizzled
  __shared__ short Vl[2][64 * 128];  // [d 64][key 128] 256B rows, swizzled
  const int tid = threadIdx.x, w = tid >> 6, lane = tid & 63;
  const int l31 = lane & 31, hi = lane >> 5;
  const int bh = blockIdx.x;
  const int y = blockIdx.y;
  // co-resident pair (id, id+256) -> (y, y+8) same bh; qt sums uniform (17)
  const int qt = (y < 8) ? y : 23 - y;
  const int q = qt * 128 + w * 32 + l31;  // this lane's q row (global in L)

  // Q fragments (b-operand): qf[dc] = Q[q][dc*16 + hi*8 .. +7]
  v8s qf[4];
  {
    const short* qrow = Qg + ((size_t)bh * 2048 + q) * 64 + hi * 8;
#pragma unroll
    for (int dc = 0; dc < 4; dc++)
      qf[dc] = *reinterpret_cast<const v8s*>(qrow + dc * 16);
  }

  float m = -1e30f, l = 0.f;
  v16f o0 = {}, o1 = {};  // O^T, d = df*32 + (r&3)+8*(r>>2)+4*hi, col q=l31

  const short* kb = Kg + (size_t)bh * 2048 * 64;
  const short* vb = VTg + (size_t)bh * 64 * 2048;

  // staging lane constants
  const int lKr = lane >> 3;                       // K: row-in-group 0..7
  const int lKc = ((lane & 7) ^ lKr) * 8;          // K: swizzled short col
  const int lVr = lane >> 4;                       // V: row-in-group 0..3
  const int w4 = w * 4;

  const int nt = qt + 1;
  int c = 0;
#define STAGE(kt_, cc_)                                                        \
  {                                                                            \
    _Pragma("unroll") for (int i = 0; i < 4; i++) {                            \
      int ii = w4 + i;                                                         \
      GLDS16(kb + (size_t)((kt_)*128 + ii * 8 + lKr) * 64 + lKc,               \
             &Kl[cc_][ii * 512]);                                              \
      int vr = ii * 4 + lVr;                                                   \
      GLDS16(vb + (size_t)vr * 2048 + (kt_)*128 + ((lane & 15) ^ (vr & 7)) * 8,\
             &Vl[cc_][ii * 512]);                                              \
    }                                                                          \
  }
  STAGE(0, 0);

  const int rx = (l31 & 7) << 4;       // xor swizzle for compute reads
  const int krb = l31 * 128;           // K row byte (128B rows)
  const int vrb = l31 * 256;           // V row byte (256B rows)

  for (int kt = 0; kt < nt; ++kt) {
    __syncthreads();  // drains vmcnt -> buf c ready
    if (kt + 1 < nt) STAGE(kt + 1, c ^ 1);

    // ---- QK^T (swapped): s{st} = S^T for keys kt*128 + st*32 + [0..31]
    v16f s0 = {}, s1 = {}, s2 = {}, s3 = {};
    const char* Klc = reinterpret_cast<const char*>(Kl[c]);
    __builtin_amdgcn_s_setprio(1);
#pragma unroll
    for (int dc = 0; dc < 4; dc++) {
      int cb = (dc * 32 + hi * 16) ^ rx;
      v8s k0 = *reinterpret_cast<const v8s*>(Klc + krb + cb);
      v8s k1 = *reinterpret_cast<const v8s*>(Klc + 4096 + krb + cb);
      v8s k2 = *reinterpret_cast<const v8s*>(Klc + 8192 + krb + cb);
      v8s k3 = *reinterpret_cast<const v8s*>(Klc + 12288 + krb + cb);
      s0 = mfma32(k0, qf[dc], s0);
      s1 = mfma32(k1, qf[dc], s1);
      s2 = mfma32(k2, qf[dc], s2);
      s3 = mfma32(k3, qf[dc], s3);
    }
    __builtin_amdgcn_s_setprio(0);

    // ---- causal mask (diagonal tile only)
    if (kt == qt) {
      int kb0 = kt * 128 + 4 * hi;
#pragma unroll
      for (int r = 0; r < 16; r++) {
        int kv = kb0 + (r & 3) + 8 * (r >> 2);
        if (kv > q) s0[r] = -1e30f;
        if (kv + 32 > q) s1[r] = -1e30f;
        if (kv + 64 > q) s2[r] = -1e30f;
        if (kv + 96 > q) s3[r] = -1e30f;
      }
    }

    // ---- online softmax (log2 domain; defer-max THR=8)
    float pm = s0[0];
#pragma unroll
    for (int r = 1; r < 16; r++) pm = fmaxf(pm, s0[r]);
#pragma unroll
    for (int r = 0; r < 16; r++) pm = fmaxf(pm, s1[r]);
#pragma unroll
    for (int r = 0; r < 16; r++) pm = fmaxf(pm, s2[r]);
#pragma unroll
    for (int r = 0; r < 16; r++) pm = fmaxf(pm, s3[r]);
    pm = fmaxf(pm, __shfl_xor(pm, 32, 64));  // cross-half row max
    if (__any(pm - m > 8.0f)) {
      float mn = fmaxf(m, pm);
      float alpha = __builtin_amdgcn_exp2f(m - mn);
      m = mn;
      l *= alpha;
#pragma unroll
      for (int r = 0; r < 16; r++) { o0[r] *= alpha; o1[r] *= alpha; }
    }
    float rs = 0.f;
#pragma unroll
    for (int r = 0; r < 16; r++) {
      s0[r] = __builtin_amdgcn_exp2f(s0[r] - m); rs += s0[r];
    }
#pragma unroll
    for (int r = 0; r < 16; r++) {
      s1[r] = __builtin_amdgcn_exp2f(s1[r] - m); rs += s1[r];
    }
#pragma unroll
    for (int r = 0; r < 16; r++) {
      s2[r] = __builtin_amdgcn_exp2f(s2[r] - m); rs += s2[r];
    }
#pragma unroll
    for (int r = 0; r < 16; r++) {
      s3[r] = __builtin_amdgcn_exp2f(s3[r] - m); rs += s3[r];
    }
    l += rs + __shfl_xor(rs, 32, 64);

    // ---- pack P to bf16 words: W{st}[t] = (p[2t], p[2t+1])
    uint W0[8], W1[8], W2[8], W3[8];
#pragma unroll
    for (int t = 0; t < 8; t++) {
      W0[t] = pack2(s0[2 * t], s0[2 * t + 1]);
      W1[t] = pack2(s1[2 * t], s1[2 * t + 1]);
      W2[t] = pack2(s2[2 * t], s2[2 * t + 1]);
      W3[t] = pack2(s3[2 * t], s3[2 * t + 1]);
    }

    // ---- PV (swapped): O^T += mfma(VT-frag, P-frag), 8 key-chunks of 16
    // words S0..S3 = Wp[base..base+3]; round-4-verified exchange:
    // hi=0 frag (S0, S1, partner S0, partner S1); sends S2,S3
    // hi=1 frag (partner S2, partner S3, S2, S3); sends S0,S1
    const char* Vlc = reinterpret_cast<const char*>(Vl[c]);
    __builtin_amdgcn_s_setprio(1);
#pragma unroll
    for (int kc = 0; kc < 8; kc++) {
      const uint* Wp = (kc < 2) ? W0 : (kc < 4) ? W1 : (kc < 6) ? W2 : W3;
      int base = (kc & 1) * 4;
      uint S0 = Wp[base + 0], S1 = Wp[base + 1];
      uint S2 = Wp[base + 2], S3 = Wp[base + 3];
      uint x0 = __shfl_xor(hi ? S0 : S2, 32, 64);
      uint x1 = __shfl_xor(hi ? S1 : S3, 32, 64);
      uint4 uf;
      uf.x = hi ? x0 : S0;
      uf.y = hi ? x1 : S1;
      uf.z = hi ? S2 : x0;
      uf.w = hi ? S3 : x1;
      v8s pf = __builtin_bit_cast(v8s, uf);
      int cb = (kc * 32 + hi * 16) ^ rx;
      v8s v0 = *reinterpret_cast<const v8s*>(Vlc + vrb + cb);
      v8s v1 = *reinterpret_cast<const v8s*>(Vlc + 8192 + vrb + cb);
      o0 = mfma32(v0, pf, o0);
      o1 = mfma32(v1, pf, o1);
    }
    __builtin_amdgcn_s_setprio(0);
    c ^= 1;
  }

  // ---- epilogue: ctx[bb*2048 + q][h*64 + d] = O^T[d][q] / l
  const int h = bh & 15, bb = bh >> 4;
  float inv = 1.0f / l;
  short* orow = ctx + ((size_t)(bb * 2048 + q)) * 1024 + h * 64;
#pragma unroll
  for (int df = 0; df < 2; df++) {
#pragma unroll
    for (int g = 0; g < 4; g++) {
      short4 st;
      const v16f& o = df ? o1 : o0;
      st.x = f2bf(o[g * 4 + 0] * inv);
      st.y = f2bf(o[g * 4 + 1] * inv);
      st.z = f2bf(o[g * 4 + 2] * inv);
      st.w = f2bf(o[g * 4 + 3] * inv);
      *reinterpret_cast<short4*>(orow + df * 32 + 8 * g + 4 * hi) = st;
    }
  }
}

extern "C" void kernel_launch(void* const* d_in, const int* in_sizes, int n_in,
                              void* d_out, int out_size, void* d_ws,
                              size_t ws_size, hipStream_t stream) {
  (void)in_sizes; (void)n_in; (void)out_size; (void)ws_size;
  const float* x = (const float*)d_in[0];
  // d_in[1] = causal_mask (implemented analytically)
  const float* wq = (const float*)d_in[2];
  const float* bq = (const float*)d_in[3];
  const float* wk = (const float*)d_in[4];
  const float* bk = (const float*)d_in[5];
  const float* wv = (const float*)d_in[6];
  const float* bv = (const float*)d_in[7];
  const float* wo = (const float*)d_in[8];
  const float* bo = (const float*)d_in[9];

  char* ws = (char*)d_ws;
  short* xb = (short*)(ws);                      // 8 MB (reused as ctx later)
  short* wqkvT = (short*)(ws + (8u << 20));      // 6 MB
  short* woT = (short*)(ws + (14u << 20));       // 2 MB
  short* Qb = (short*)(ws + (16u << 20));        // 8 MB
  short* Kb = (short*)(ws + (24u << 20));        // 8 MB
  short* VTb = (short*)(ws + (32u << 20));       // 8 MB
  short* ctx = xb;                               // alias: xb dead after QKV GEMM
  float* out = (float*)d_out;

  k_cvt<<<4096, 256, 0, stream>>>(x, xb);
  k_tw<<<dim3(32, 32, 4), dim3(32, 8), 0, stream>>>(wq, wk, wv, wo, wqkvT, woT);
  k_gemm<0><<<dim3(24, 32), 256, 0, stream>>>(xb, wqkvT, bq, bk, bv, Qb, Kb,
                                              VTb, nullptr);
  k_flash<<<dim3(32, 16), 256, 0, stream>>>(Qb, Kb, VTb, ctx);
  k_gemm<1><<<dim3(8, 32), 256, 0, stream>>>(ctx, woT, bo, nullptr, nullptr,
                                             nullptr, nullptr, nullptr, out);
}